// Round 6
// baseline (88.139 us; speedup 1.0000x reference)
//
#include <hip/hip_runtime.h>
#include <math.h>

// Problem constants (fixed by setup_inputs)
constexpr int B_ = 8;
constexpr int N_ = 16384;
constexpr int M_ = 1024;
constexpr int C_ = 256;
constexpr int NCHUNK = 8;
constexpr int CHUNK = M_ / NCHUNK;  // 128
constexpr int KEEP = 4;             // per-chunk survivors
constexpr int TOPK_BLOCK = 512;     // threads/block; each thread owns 2 points
                                    // -> 8-wave blocks, ~4 blocks/CU, 4 K$ streams (8KB)

// native 4-float vector for __builtin_nontemporal_store (HIP's float4 is a
// class type the builtin rejects; ext_vector_type is accepted).
typedef float nfloat4 __attribute__((ext_vector_type(4)));

// 4-deep sorted-insert network on POSITIVE floats (P0<=P1<=P2<=P3 invariant).
// min + 3x v_med3_f32, all VOP3-legal, no SGPR operands.
#define INSERT4(P, u)                                              \
  {                                                                \
    const float o0 = P##0, o1 = P##1, o2 = P##2;                   \
    P##0 = fminf(o0, (u));                                         \
    P##1 = __builtin_amdgcn_fmed3f(o0, P##1, (u));                 \
    P##2 = __builtin_amdgcn_fmed3f(o1, P##2, (u));                 \
    P##3 = __builtin_amdgcn_fmed3f(o2, P##3, (u));                 \
  }

// ---------------------------------------------------------------------------
// Kernel 0 (fused prep): blocks [0,32) pack centroids; blocks [32, 32+2048)
// transpose centroid_f [B,C,M] -> fT [B,M,C] via 32x32 LDS tiles (+1 pad).
// ---------------------------------------------------------------------------
__global__ __launch_bounds__(256) void prep_kernel(
    const float* __restrict__ cxyz,  // [B, M, 3]
    const float* __restrict__ cf,    // [B, C, M]
    float* __restrict__ csoa,        // [B][NCHUNK][CHUNK/2][8]
    float4* __restrict__ cpack,      // [B*M]
    float* __restrict__ fT)          // [B, M, C]
{
  __shared__ float tile[32][33];
  const int tx = threadIdx.x;  // 0..31
  const int ty = threadIdx.y;  // 0..7
  if (blockIdx.x < 32) {
    // ---- pack role ----
    const int i = blockIdx.x * 256 + (ty * 32 + tx);  // global centroid id
    if (i < B_ * M_) {
      const int b = i >> 10;         // / M_
      const int m = i & (M_ - 1);
      const int chunk = m >> 7;      // / CHUNK
      const int mi = m & (CHUNK - 1);
      const int pair = mi >> 1;
      const int sub = mi & 1;
      const float x = cxyz[3 * i + 0];
      const float y = cxyz[3 * i + 1];
      const float z = cxyz[3 * i + 2];
      const float w = x * x + y * y + z * z;
      float* pb = csoa + ((((size_t)b * NCHUNK + chunk) * (CHUNK / 2)) + pair) * 8 + sub;
      pb[0] = x; pb[2] = y; pb[4] = z; pb[6] = w;
      cpack[i] = make_float4(x, y, z, w);
    }
  } else {
    // ---- transpose role ----
    const int bid = blockIdx.x - 32;       // 0..2047
    const int m0 = (bid & 31) * 32;        // M/32 = 32
    const int c0 = ((bid >> 5) & 7) * 32;  // C/32 = 8
    const int b = bid >> 8;
    const float* fb = cf + (size_t)b * C_ * M_;
    float* ftb = fT + (size_t)b * M_ * C_;
#pragma unroll
    for (int j = 0; j < 32; j += 8)
      tile[ty + j][tx] = fb[(size_t)(c0 + ty + j) * M_ + (m0 + tx)];
    __syncthreads();
#pragma unroll
    for (int j = 0; j < 32; j += 8)
      ftb[(size_t)(m0 + ty + j) * C_ + (c0 + tx)] = tile[tx][ty + j];
  }
}

// ---------------------------------------------------------------------------
// Kernel 1: chunked top-4, 2 POINTS PER THREAD (R6 change, topk-only).
// The 8 scalar-loaded csoa values per iteration now feed 4 keys (2 per
// point) instead of 2: per-key s_load traffic, waitcnts, and loop overhead
// halve; per-key VALU math (3 fma + add + pack + INSERT4) is byte-identical
// per point. Four independent insert chains (A/B p0, C/D p1) widen ILP.
// Points n and n+512: both coalesced, same chunk stream.
// DO NOT fuse other roles into this kernel (R1/R2 lesson, 167-183us).
// ---------------------------------------------------------------------------
__global__ __launch_bounds__(TOPK_BLOCK) void topk_chunk_kernel(
    const float* __restrict__ xyz,   // [B, N, 3]
    const float* __restrict__ csoa,  // [B][NCHUNK][CHUNK/2][8]
    unsigned* __restrict__ cand)     // [B*N][NCHUNK]: 4 packed 8-bit indices
{
  const int b = blockIdx.z;
  const int chunk = blockIdx.y;
  const int n = blockIdx.x * (TOPK_BLOCK * 2) + threadIdx.x;  // point 0
  const size_t p0 = (size_t)b * N_ + n;
  const size_t p1 = p0 + TOPK_BLOCK;                          // point 1

  const float* __restrict__ cb =
      csoa + (((size_t)b * NCHUNK + chunk) * (CHUNK / 2)) * 8;

  const float* xq = xyz + p0 * 3;
  const float q0 = xq[0], q1 = xq[1], q2 = xq[2];
  const float nq0 = -2.f * q0, nq1 = -2.f * q1, nq2 = -2.f * q2;
  const float q2p1 = fmaf(q0, q0, fmaf(q1, q1, fmaf(q2, q2, 1.0f)));

  const float* xr = xyz + p1 * 3;
  const float r0 = xr[0], r1 = xr[1], r2 = xr[2];
  const float nr0 = -2.f * r0, nr1 = -2.f * r1, nr2 = -2.f * r2;
  const float r2p1 = fmaf(r0, r0, fmaf(r1, r1, fmaf(r2, r2, 1.0f)));

  float A0 = INFINITY, A1 = INFINITY, A2 = INFINITY, A3 = INFINITY;
  float B0 = INFINITY, B1 = INFINITY, B2 = INFINITY, B3 = INFINITY;
  float C0 = INFINITY, C1 = INFINITY, C2 = INFINITY, C3 = INFINITY;
  float D0 = INFINITY, D1 = INFINITY, D2 = INFINITY, D3 = INFINITY;

#pragma unroll 8
  for (int i = 0; i < CHUNK / 2; ++i) {
    const float* pb = cb + i * 8;
    const float c0x = pb[0], c1x = pb[1], c0y = pb[2], c1y = pb[3];
    const float c0z = pb[4], c1z = pb[5], c0w = pb[6], c1w = pb[7];
    const unsigned ie = (unsigned)(2 * i), io = (unsigned)(2 * i + 1);

    // ---- point 0 ----
    float tx = fmaf(nq0, c0x, q2p1), ty = fmaf(nq0, c1x, q2p1);
    tx = fmaf(nq1, c0y, tx); ty = fmaf(nq1, c1y, ty);
    tx = fmaf(nq2, c0z, tx); ty = fmaf(nq2, c1z, ty);
    tx += c0w; ty += c1w;  // key = d^2 + 1 > 0
    const float kx = __uint_as_float((__float_as_uint(tx) & 0xFFFFFF80u) | ie);
    const float ky = __uint_as_float((__float_as_uint(ty) & 0xFFFFFF80u) | io);
    INSERT4(A, kx);
    INSERT4(B, ky);

    // ---- point 1 ----
    float ux = fmaf(nr0, c0x, r2p1), uy = fmaf(nr0, c1x, r2p1);
    ux = fmaf(nr1, c0y, ux); uy = fmaf(nr1, c1y, uy);
    ux = fmaf(nr2, c0z, ux); uy = fmaf(nr2, c1z, uy);
    ux += c0w; uy += c1w;
    const float lx = __uint_as_float((__float_as_uint(ux) & 0xFFFFFF80u) | ie);
    const float ly = __uint_as_float((__float_as_uint(uy) & 0xFFFFFF80u) | io);
    INSERT4(C, lx);
    INSERT4(D, ly);
  }
  // fold odd chains into even chains (exact running-inserts, same order
  // as the proven version: B0,B1,B2,B3 ascending)
  INSERT4(A, B0);
  INSERT4(A, B1);
  INSERT4(A, B2);
  INSERT4(A, B3);
  INSERT4(C, D0);
  INSERT4(C, D1);
  INSERT4(C, D2);
  INSERT4(C, D3);

  {
    const unsigned i0 = __float_as_uint(A0) & 127u;
    const unsigned i1 = __float_as_uint(A1) & 127u;
    const unsigned i2 = __float_as_uint(A2) & 127u;
    const unsigned i3 = __float_as_uint(A3) & 127u;
    cand[p0 * NCHUNK + chunk] = i0 | (i1 << 8) | (i2 << 16) | (i3 << 24);
  }
  {
    const unsigned i0 = __float_as_uint(C0) & 127u;
    const unsigned i1 = __float_as_uint(C1) & 127u;
    const unsigned i2 = __float_as_uint(C2) & 127u;
    const unsigned i3 = __float_as_uint(C3) & 127u;
    cand[p1 * NCHUNK + chunk] = i0 | (i1 << 8) | (i2 << 16) | (i3 << 24);
  }
}

// ---------------------------------------------------------------------------
// Kernel 2: merge 8x4 candidates -> exact global top-3 + weights. VERBATIM
// proven structure (f64 re-rank, stable strict-< insertion). Standalone so
// its ~90-VGPR f64 path sets only its own occupancy (R4 lesson).
// ---------------------------------------------------------------------------
__global__ __launch_bounds__(256) void merge_kernel(
    const float* __restrict__ xyz,     // [B, N, 3]
    const float4* __restrict__ cpack,  // [B*M]
    const unsigned* __restrict__ cand, // [B*N][NCHUNK]
    int*   __restrict__ out_idx,       // [B*N, 3]
    float* __restrict__ out_w)         // [B*N, 3]
{
  const size_t p = (size_t)blockIdx.x * 256 + threadIdx.x;
  const int b = (int)(p >> 14);  // p / N_

  const float* xp = xyz + p * 3;
  const double x0d = (double)xp[0], x1d = (double)xp[1], x2d = (double)xp[2];
  const float4* __restrict__ cb = cpack + (size_t)b * M_;

  const uint4* cw4 = (const uint4*)(cand + p * NCHUNK);
  const uint4 ca = cw4[0], cb2 = cw4[1];
  unsigned words[NCHUNK] = {ca.x, ca.y, ca.z, ca.w, cb2.x, cb2.y, cb2.z, cb2.w};

  double D0 = 1e300, D1 = 1e300, D2 = 1e300;
  int I0 = 0, I1 = 0, I2 = 0;
#pragma unroll
  for (int ch = 0; ch < NCHUNK; ++ch) {
    const unsigned w = words[ch];
#pragma unroll
    for (int j = 0; j < KEEP; ++j) {
      const int m = ch * CHUNK + (int)((w >> (8 * j)) & 255u);
      const float4 c = cb[m];
      const double cx = (double)c.x, cy = (double)c.y, cz = (double)c.z;
      const double dot = x0d * cx + x1d * cy + x2d * cz;
      const double c2d = cx * cx + cy * cy + cz * cz;
      const double kd = c2d - 2.0 * dot;
      if (kd < D2) {
        if (kd < D1) {
          D2 = D1; I2 = I1;
          if (kd < D0) { D1 = D0; I1 = I0; D0 = kd; I0 = m; }
          else         { D1 = kd; I1 = m; }
        } else {
          D2 = kd; I2 = m;
        }
      }
    }
  }

  const double xx = x0d * x0d + x1d * x1d + x2d * x2d;
  const float d0 = sqrtf(fmaxf((float)(xx + D0), 0.0f));
  const float d1 = sqrtf(fmaxf((float)(xx + D1), 0.0f));
  const float d2 = sqrtf(fmaxf((float)(xx + D2), 0.0f));
  float w0 = 1.0f / fmaxf(d0, 1e-8f);
  float w1 = 1.0f / fmaxf(d1, 1e-8f);
  float w2 = 1.0f / fmaxf(d2, 1e-8f);
  const float wsum = w0 + w1 + w2;
  w0 /= wsum; w1 /= wsum; w2 /= wsum;

  const size_t o = p * 3;
  out_idx[o + 0] = I0; out_idx[o + 1] = I1; out_idx[o + 2] = I2;
  out_w[o + 0] = w0;   out_w[o + 1] = w1;   out_w[o + 2] = w2;
}

// ---------------------------------------------------------------------------
// Kernel 3: weighted feature gather -- VERBATIM R5 (batch<->XCD swizzle +
// non-temporal output stores; 8us win over baseline).
// ---------------------------------------------------------------------------
__global__ __launch_bounds__(256) void gather_kernel(
    const float* __restrict__ fT,   // [B, M, C]
    const int*   __restrict__ idx,  // [B*N, 3]
    const float* __restrict__ w,    // [B*N, 3]
    float* __restrict__ out)        // [B, N, C]
{
  const int wid  = threadIdx.x >> 6;
  const int lane = threadIdx.x & 63;
  // batch<->XCD swizzle: 32768 groups of 4 points; 4096 groups per batch.
  const int g = (blockIdx.x & 7) * 4096 + (blockIdx.x >> 3);
  const size_t p = (size_t)g * 4 + wid;  // global point id
  const int b = (int)(p >> 14);          // p / N_  (== blockIdx.x & 7)

  const size_t o = p * 3;
  const int i0 = idx[o + 0], i1 = idx[o + 1], i2 = idx[o + 2];
  const float w0 = w[o + 0], w1 = w[o + 1], w2 = w[o + 2];

  const float4* f4 = (const float4*)(fT + (size_t)b * M_ * C_);
  float4 a = f4[(size_t)i0 * (C_ / 4) + lane];
  float4 bb = f4[(size_t)i1 * (C_ / 4) + lane];
  float4 c = f4[(size_t)i2 * (C_ / 4) + lane];

  nfloat4 r;
  r.x = w0 * a.x + w1 * bb.x + w2 * c.x;
  r.y = w0 * a.y + w1 * bb.y + w2 * c.y;
  r.z = w0 * a.z + w1 * bb.z + w2 * c.z;
  r.w = w0 * a.w + w1 * bb.w + w2 * c.w;

  __builtin_nontemporal_store(r, &((nfloat4*)out)[p * (C_ / 4) + lane]);
}

extern "C" void kernel_launch(void* const* d_in, const int* in_sizes, int n_in,
                              void* d_out, int out_size, void* d_ws, size_t ws_size,
                              hipStream_t stream) {
  const float* xyz  = (const float*)d_in[0];  // [B, N, 3]
  const float* cxyz = (const float*)d_in[1];  // [B, M, 3]
  const float* cf   = (const float*)d_in[2];  // [B, C, M]
  float* out = (float*)d_out;                 // [B, N, C]

  char* ws = (char*)d_ws;
  const size_t npts = (size_t)B_ * N_;

  int*    idxbuf = (int*)ws;                              // npts*3 ints
  float*  wbuf   = (float*)(ws + npts * 3 * sizeof(int)); // npts*3 floats
  size_t  off    = npts * 3 * 8;
  float4* cpack  = (float4*)(ws + off);                   // B*M float4 (128 KB)
  off += (size_t)B_ * M_ * sizeof(float4);
  float*  csoa   = (float*)(ws + off);                    // B*M*4 floats (128 KB)
  off += (size_t)B_ * M_ * 4 * sizeof(float);
  off = (off + 15) & ~(size_t)15;
  char*   region = ws + off;
  unsigned* cand = (unsigned*)region;  // npts*NCHUNK*4B = 4.2 MB
  size_t cand_bytes = (npts * (size_t)NCHUNK * 4 + 255) & ~(size_t)255;
  float* fT = (float*)(region + cand_bytes);  // B*M*C floats = 8 MB

  prep_kernel<<<dim3(32 + 2048), dim3(32, 8), 0, stream>>>(
      cxyz, cf, csoa, cpack, fT);
  topk_chunk_kernel<<<dim3(N_ / (TOPK_BLOCK * 2), NCHUNK, B_), TOPK_BLOCK, 0, stream>>>(
      xyz, csoa, cand);
  merge_kernel<<<(unsigned)(npts / 256), 256, 0, stream>>>(
      xyz, cpack, cand, idxbuf, wbuf);
  gather_kernel<<<(unsigned)(npts / 4), 256, 0, stream>>>(fT, idxbuf, wbuf, out);
}